// Round 13
// baseline (56.444 us; speedup 1.0000x reference)
//
#include <hip/hip_runtime.h>
#include <math.h>

// Wong-Wang multi-class decision, forward only — FLOAT64 dynamics (r4-r6,r8-r12 passed).
// r13: zero-issue-cost spine-level cuts (regime: 56% VALU issue / 44% in-order stall):
//  * SPECULATIVE-SEED RCP: y0 = rcp(den_a), den_a = fma(-Qmid, sc, DEN1) from the
//    deg-8 partial Qmid (1 level before p). Seed err <= 5e-9 (vanishes as z^7 at
//    the den~0 pole); corr-fold vs TRUE den converges quadratically -> ~2e-16,
//    same 1-ulp class as before. rcp TRANS latency now overlaps p/den. (+1 fma)
//  * crossing test on cand, not s (exact: s9-branch crossings imply a prior
//    recorded crossing; cand>thr implies s=cand) — compare doesn't wait on fmax.
// Kept from r12: tz-space noise recursion, sc via lshl-add, paired dec update,
// launch_bounds(256,1), single-LN2 reduction, deg-10 Estrin Taylor, DEN1 fold,
// relu-as-max, butterfly quad-sum, SALU-uniform loads.

#define T_STEPS 500
#define BATCH   16384
#define STRIDE  (BATCH * 4)

template <int CTRL>
__device__ __forceinline__ double qperm_d(double v) {
    long long l = __double_as_longlong(v);
    int lo = (int)(l & 0xFFFFFFFFLL);
    int hi = (int)(l >> 32);
    lo = __builtin_amdgcn_mov_dpp(lo, CTRL, 0xF, 0xF, true);
    hi = __builtin_amdgcn_mov_dpp(hi, CTRL, 0xF, 0xF, true);
    return __longlong_as_double(((long long)hi << 32) | (unsigned int)lo);
}

struct WWConst {
    double ZJo, ZCJdmJo;     // ZC*Jo, ZC*(Jd-Jo)
    double ZCsig, K2;        // ZC*sigma, ZC*base2 + ZK*(1-decay)
    double decay, thr;
};

// one dynamics step; updates s and tz, returns cand (for the crossing test)
__device__ __forceinline__ double ww_step(
    double& s, double& tz, float e, const WWConst& C)
{
    const double MAGIC = 6755399441055744.0;               // 1.5 * 2^52
    const double L2E   = 1.4426950408889634074;
    const double LN2   = 6.93147180559945286227e-01;
    const double DEN1  = 1.0 + 1e-6;
    const double G     = -(0.00641 / 0.154);               // up2 = G*(1-s)

    // butterfly quad sum (includes own s): sum4 = s0+s1+s2+s3
    double v1   = s + qperm_d<0xB1>(s);
    double sum4 = v1 + qperm_d<0x4E>(v1);
    double w2   = __builtin_fma(C.ZCJdmJo, s, tz);   // ZC*(Jd-Jo)*s + tz
    double up2  = __builtin_fma(-G, s, G);           // G*(1-s), early
    double s9   = 0.9 * s;                           // early
    // z = -0.154*(270x - 108),  x = Jo*sum4 + (Jd-Jo)*s + t1
    double z = __builtin_fma(C.ZJo, sum4, w2);

    double tmag = __builtin_fma(L2E, z, MAGIC);
    double m    = up2 * z;                           // parallel with exp chain
    double nd   = tmag - MAGIC;
    double r    = __builtin_fma(-nd, LN2, z);        // single-constant reduction

    // deg-10 Estrin Taylor for exp(r)
    double r2 = r * r;
    double P0 = 1.0 + r;
    double P1 = __builtin_fma(r, 1.0 / 6.0,      0.5);
    double P2 = __builtin_fma(r, 1.0 / 120.0,    1.0 / 24.0);
    double P3 = __builtin_fma(r, 1.0 / 5040.0,   1.0 / 720.0);
    double P4 = __builtin_fma(r, 1.0 / 362880.0, 1.0 / 40320.0);
    double r4 = r2 * r2;
    double Q0 = __builtin_fma(r2, P1, P0);
    double Q1 = __builtin_fma(r2, P3, P2);
    double Q2 = __builtin_fma(r2, 1.0 / 3628800.0, P4);
    double r8 = r4 * r4;
    double Qmid = __builtin_fma(r4, Q1, Q0);         // deg-8 partial
    double p    = __builtin_fma(r8, Q2, Qmid);       // full deg-10

    // sc = 2^n: hi word = (lo32(tmag)<<20) + 0x3FF00000
    int   nlo = __double2loint(tmag);
    double sc = __hiloint2double((nlo << 20) + 0x3FF00000, 0);

    // speculative seed: den_a uses Qmid (ready 1 level before p)
    double den_a = __builtin_fma(-Qmid, sc, DEN1);
    double y0    = __builtin_amdgcn_rcp(den_a);      // TRANS latency overlaps p/den
    double den   = __builtin_fma(-p, sc, DEN1);      // true denominator

    // y = y0*(2 - den*y0): quadratic clean-up vs TRUE den (err ~2e-16)
    double corr = __builtin_fma(-den, y0, 2.0);
    double my0  = m * y0;
    double cand = __builtin_fma(my0, corr, s9);
    s = fmax(cand, s9);                              // relu folded into max

    // noise chain, tz-space only:
    tz = __builtin_fma(tz, C.decay,
                       __builtin_fma(C.ZCsig, (double)e, C.K2));
    return cand;
}

__global__ __launch_bounds__(256, 1)
void ww_kernel(const float* __restrict__ in_sig,
               const float* __restrict__ eps0,
               const float* __restrict__ eps,
               const float* __restrict__ Jm,
               const float* __restrict__ pJext,
               const float* __restrict__ pI0,
               const float* __restrict__ pNa,
               const float* __restrict__ pThr,
               float* __restrict__ out)
{
    const int gid = blockIdx.x * blockDim.x + threadIdx.x; // 0..65535

    const double Jext = (double)pJext[0];
    const double I0   = (double)pI0[0];
    const double na   = (double)pNa[0];
    const double ZC   = -0.154 * 270.0;
    const double ZK   =  0.154 * 108.0;

    WWConst C;
    const double Jd = (double)Jm[0];   // diagonal
    const double Jo = (double)Jm[1];   // off-diagonal
    C.ZJo     = ZC * Jo;
    C.ZCJdmJo = ZC * (Jd - Jo);
    C.decay   = exp(-5.0);             // exp(-DT/TAU_AMPA)
    const double sigma = na * sqrt((1.0 - exp(-10.0)) / 2.0);
    C.ZCsig   = ZC * sigma;
    C.thr     = (double)pThr[0];

    const double base  = I0 + Jext * (double)in_sig[gid];
    const double base2 = base * (1.0 - C.decay);
    C.K2 = __builtin_fma(ZC, base2, ZK * (1.0 - C.decay));

    double s   = 0.1;
    double t10 = base + (double)eps0[gid] * na;    // base + inoise_0
    double tz  = __builtin_fma(ZC, t10, ZK);
    int    dec = 0x3FFFFFFF;

    // 10-step double-buffered register prefetch; 500 = 25 blocks * 20 steps.
    const float* pu = eps;
    float eA[10], eB[10];
#pragma unroll
    for (int i = 0; i < 10; ++i) eA[i] = pu[(size_t)i * STRIDE + gid];
    pu += (size_t)10 * STRIDE;

    const double thr = C.thr;
    for (int blk = 0; blk < 25; ++blk) {
        const int t0 = blk * 20;
#pragma unroll
        for (int i = 0; i < 10; ++i)
            eB[i] = pu[(size_t)i * STRIDE + gid];
        pu += (size_t)10 * STRIDE;
#pragma unroll
        for (int i = 0; i < 10; i += 2) {
            const bool c0 = (ww_step(s, tz, eA[i],     C) > thr);
            const bool c1 = (ww_step(s, tz, eA[i + 1], C) > thr);
            const int ci = c0 ? (t0 + i) : (c1 ? (t0 + i + 1) : 0x3FFFFFFF);
            dec = min(dec, ci);
        }
        if (blk < 24) {
#pragma unroll
            for (int i = 0; i < 10; ++i)
                eA[i] = pu[(size_t)i * STRIDE + gid];
            pu += (size_t)10 * STRIDE;
        }
#pragma unroll
        for (int i = 0; i < 10; i += 2) {
            const bool c0 = (ww_step(s, tz, eB[i],     C) > thr);
            const bool c1 = (ww_step(s, tz, eB[i + 1], C) > thr);
            const int ci = c0 ? (t0 + 10 + i) : (c1 ? (t0 + 11 + i) : 0x3FFFFFFF);
            dec = min(dec, ci);
        }
    }

    const int d = min(dec, T_STEPS - 1);   // never-crossed -> T-1
    out[gid] = ((float)d * 10.0f) / 1000.0f;
}

extern "C" void kernel_launch(void* const* d_in, const int* in_sizes, int n_in,
                              void* d_out, int out_size, void* d_ws, size_t ws_size,
                              hipStream_t stream) {
    const float* in_sig = (const float*)d_in[0];
    const float* eps0   = (const float*)d_in[1];
    const float* eps    = (const float*)d_in[2];
    const float* Jm     = (const float*)d_in[3];
    const float* pJext  = (const float*)d_in[4];
    const float* pI0    = (const float*)d_in[5];
    const float* pNa    = (const float*)d_in[6];
    const float* pThr   = (const float*)d_in[7];
    float* out = (float*)d_out;

    ww_kernel<<<(BATCH * 4) / 256, 256, 0, stream>>>(
        in_sig, eps0, eps, Jm, pJext, pI0, pNa, pThr, out);
}

// Round 14
// 55.145 us; speedup vs baseline: 1.0236x; 1.0236x over previous
//
#include <hip/hip_runtime.h>
#include <math.h>

// Wong-Wang multi-class decision, forward only — FLOAT64 dynamics.
// r14 = EXACT REVERT to r12 (measured best: 54.7 µs, absmax 0.078125).
// r13 post-mortem: speculative-seed rcp added 1 fma (+0.8 µs issue) for zero
// real spine-level gain (rcp couldn't start before sc/p completed anyway) and
// the cand-return added a live-range across the step boundary -> 56.4 µs.
// Regime (r12 counters): ~56% issue / ~44% in-order stall, 1 wave/SIMD pinned
// by grid (65536 = B*C lanes), FETCH 64 MB @ 11% HBM — structural limit:
// 500-step serial f64 chain; no further zero-cost levers identified.

#define T_STEPS 500
#define BATCH   16384
#define STRIDE  (BATCH * 4)

template <int CTRL>
__device__ __forceinline__ double qperm_d(double v) {
    long long l = __double_as_longlong(v);
    int lo = (int)(l & 0xFFFFFFFFLL);
    int hi = (int)(l >> 32);
    lo = __builtin_amdgcn_mov_dpp(lo, CTRL, 0xF, 0xF, true);
    hi = __builtin_amdgcn_mov_dpp(hi, CTRL, 0xF, 0xF, true);
    return __longlong_as_double(((long long)hi << 32) | (unsigned int)lo);
}

struct WWConst {
    double ZJo, ZCJdmJo;     // ZC*Jo, ZC*(Jd-Jo)
    double ZCsig, K2;        // ZC*sigma, ZC*base2 + ZK*(1-decay)
    double decay, thr;
};

// one dynamics step; updates s and tz (dec handled by caller)
__device__ __forceinline__ void ww_step(
    double& s, double& tz, float e, const WWConst& C)
{
    const double MAGIC = 6755399441055744.0;               // 1.5 * 2^52
    const double L2E   = 1.4426950408889634074;
    const double LN2   = 6.93147180559945286227e-01;
    const double DEN1  = 1.0 + 1e-6;
    const double G     = -(0.00641 / 0.154);               // up2 = G*(1-s)

    // butterfly quad sum (includes own s): sum4 = s0+s1+s2+s3
    double v1   = s + qperm_d<0xB1>(s);
    double sum4 = v1 + qperm_d<0x4E>(v1);
    double w2   = __builtin_fma(C.ZCJdmJo, s, tz);   // ZC*(Jd-Jo)*s + tz
    double up2  = __builtin_fma(-G, s, G);           // G*(1-s), early
    double s9   = 0.9 * s;                           // early
    // z = -0.154*(270x - 108),  x = Jo*sum4 + (Jd-Jo)*s + t1
    double z = __builtin_fma(C.ZJo, sum4, w2);

    double tmag = __builtin_fma(L2E, z, MAGIC);
    double m    = up2 * z;                           // parallel with exp chain
    double nd   = tmag - MAGIC;
    double r    = __builtin_fma(-nd, LN2, z);        // single-constant reduction

    // deg-10 Estrin Taylor for exp(r)
    double r2 = r * r;
    double P0 = 1.0 + r;
    double P1 = __builtin_fma(r, 1.0 / 6.0,      0.5);
    double P2 = __builtin_fma(r, 1.0 / 120.0,    1.0 / 24.0);
    double P3 = __builtin_fma(r, 1.0 / 5040.0,   1.0 / 720.0);
    double P4 = __builtin_fma(r, 1.0 / 362880.0, 1.0 / 40320.0);
    double r4 = r2 * r2;
    double Q0 = __builtin_fma(r2, P1, P0);
    double Q1 = __builtin_fma(r2, P3, P2);
    double Q2 = __builtin_fma(r2, 1.0 / 3628800.0, P4);
    double r8 = r4 * r4;
    double p  = __builtin_fma(r8, Q2, __builtin_fma(r4, Q1, Q0));

    // sc = 2^n: hi word = (lo32(tmag)<<20) + 0x3FF00000  (one v_lshl_add_u32)
    int   nlo = __double2loint(tmag);
    double sc = __hiloint2double((nlo << 20) + 0x3FF00000, 0);

    // den = 1.000001 - p*2^n
    double den = __builtin_fma(-p, sc, DEN1);

    // y ~ 1/den via rcp + folded Newton; cand = m*y0*(2-den*y0) + s9
    double y0   = __builtin_amdgcn_rcp(den);
    double corr = __builtin_fma(-den, y0, 2.0);
    double my0  = m * y0;
    double cand = __builtin_fma(my0, corr, s9);
    s = fmax(cand, s9);                              // relu folded into max

    // noise chain, tz-space only (t1 eliminated):
    tz = __builtin_fma(tz, C.decay,
                       __builtin_fma(C.ZCsig, (double)e, C.K2));
}

__global__ __launch_bounds__(256, 1)
void ww_kernel(const float* __restrict__ in_sig,
               const float* __restrict__ eps0,
               const float* __restrict__ eps,
               const float* __restrict__ Jm,
               const float* __restrict__ pJext,
               const float* __restrict__ pI0,
               const float* __restrict__ pNa,
               const float* __restrict__ pThr,
               float* __restrict__ out)
{
    const int gid = blockIdx.x * blockDim.x + threadIdx.x; // 0..65535

    const double Jext = (double)pJext[0];
    const double I0   = (double)pI0[0];
    const double na   = (double)pNa[0];
    const double ZC   = -0.154 * 270.0;
    const double ZK   =  0.154 * 108.0;

    WWConst C;
    const double Jd = (double)Jm[0];   // diagonal
    const double Jo = (double)Jm[1];   // off-diagonal
    C.ZJo     = ZC * Jo;
    C.ZCJdmJo = ZC * (Jd - Jo);
    C.decay   = exp(-5.0);             // exp(-DT/TAU_AMPA)
    const double sigma = na * sqrt((1.0 - exp(-10.0)) / 2.0);
    C.ZCsig   = ZC * sigma;
    C.thr     = (double)pThr[0];

    const double base  = I0 + Jext * (double)in_sig[gid];
    const double base2 = base * (1.0 - C.decay);
    C.K2 = __builtin_fma(ZC, base2, ZK * (1.0 - C.decay));

    double s   = 0.1;
    double t10 = base + (double)eps0[gid] * na;    // base + inoise_0
    double tz  = __builtin_fma(ZC, t10, ZK);
    int    dec = 0x3FFFFFFF;

    // 10-step double-buffered register prefetch; 500 = 25 blocks * 20 steps.
    const float* pu = eps;
    float eA[10], eB[10];
#pragma unroll
    for (int i = 0; i < 10; ++i) eA[i] = pu[(size_t)i * STRIDE + gid];
    pu += (size_t)10 * STRIDE;

    const double thr = C.thr;
    for (int blk = 0; blk < 25; ++blk) {
        const int t0 = blk * 20;
#pragma unroll
        for (int i = 0; i < 10; ++i)
            eB[i] = pu[(size_t)i * STRIDE + gid];
        pu += (size_t)10 * STRIDE;
#pragma unroll
        for (int i = 0; i < 10; i += 2) {
            ww_step(s, tz, eA[i], C);
            const bool c0 = (s > thr);
            ww_step(s, tz, eA[i + 1], C);
            const bool c1 = (s > thr);
            const int ci = c0 ? (t0 + i) : (c1 ? (t0 + i + 1) : 0x3FFFFFFF);
            dec = min(dec, ci);
        }
        if (blk < 24) {
#pragma unroll
            for (int i = 0; i < 10; ++i)
                eA[i] = pu[(size_t)i * STRIDE + gid];
            pu += (size_t)10 * STRIDE;
        }
#pragma unroll
        for (int i = 0; i < 10; i += 2) {
            ww_step(s, tz, eB[i], C);
            const bool c0 = (s > thr);
            ww_step(s, tz, eB[i + 1], C);
            const bool c1 = (s > thr);
            const int ci = c0 ? (t0 + 10 + i) : (c1 ? (t0 + 11 + i) : 0x3FFFFFFF);
            dec = min(dec, ci);
        }
    }

    const int d = min(dec, T_STEPS - 1);   // never-crossed -> T-1
    out[gid] = ((float)d * 10.0f) / 1000.0f;
}

extern "C" void kernel_launch(void* const* d_in, const int* in_sizes, int n_in,
                              void* d_out, int out_size, void* d_ws, size_t ws_size,
                              hipStream_t stream) {
    const float* in_sig = (const float*)d_in[0];
    const float* eps0   = (const float*)d_in[1];
    const float* eps    = (const float*)d_in[2];
    const float* Jm     = (const float*)d_in[3];
    const float* pJext  = (const float*)d_in[4];
    const float* pI0    = (const float*)d_in[5];
    const float* pNa    = (const float*)d_in[6];
    const float* pThr   = (const float*)d_in[7];
    float* out = (float*)d_out;

    ww_kernel<<<(BATCH * 4) / 256, 256, 0, stream>>>(
        in_sig, eps0, eps, Jm, pJext, pI0, pNa, pThr, out);
}